// Round 1
// baseline (13251.686 us; speedup 1.0000x reference)
//
#include <hip/hip_runtime.h>

// Problem constants (from reference)
#define DD   128   // D
#define TT   128   // T
#define QDIM 256   // D + T
#define KDIM 384   // 2D + T
#define KN   10    // K neighbors
#define NH   2     // heads
#define HDIM 128   // QDIM / NH
#define BLK  256

// k/v/scores/softmax now live in registers; only cross-thread data in LDS.
struct Scratch {
    float att[QDIM];     // attn @ V result (per output element)
    float o[QDIM];       // Wo projection result
    float h1[DD];        // fc1 hidden
    float part[4][KN];   // per-wave score partial sums
};

__device__ __forceinline__ float dot4(const float* __restrict__ w,
                                      const float* __restrict__ x, int len) {
    const float4* w4 = reinterpret_cast<const float4*>(w);
    const float4* x4 = reinterpret_cast<const float4*>(x);
    float acc = 0.f;
    for (int g = 0; g < len / 4; ++g) {
        float4 a = w4[g], b = x4[g];
        acc += a.x * b.x + a.y * b.y + a.z * b.z + a.w * b.w;
    }
    return acc;
}

// One temporal-attention row. qin [QDIM] and kin [KN][KDIM] must be fully
// built in LDS and covered by a __syncthreads() BEFORE the call. Ends with
// __syncthreads(); result (DD floats) in out (LDS). Weight pointers must be
// pre-offset to the layer slice.
__device__ void attn_row(int tid,
                         const float* __restrict__ qin,
                         const float (* __restrict__ kin)[KDIM],
                         unsigned maskbits, int invalid,
                         const float* __restrict__ Wq, const float* __restrict__ bq,
                         const float* __restrict__ Wk, const float* __restrict__ bk,
                         const float* __restrict__ Wv, const float* __restrict__ bv,
                         const float* __restrict__ Wo, const float* __restrict__ bo,
                         const float* __restrict__ f1w, const float* __restrict__ f1b,
                         const float* __restrict__ f2w, const float* __restrict__ f2b,
                         Scratch* __restrict__ s,
                         float* __restrict__ out)
{
    const int o = tid;

    // ---- Q projection (own output element only) ----
    float q_o = bq[o] + dot4(Wq + (long)o * QDIM, qin, QDIM);

    // ---- K/V projections: thread o computes k[kk][o], v[kk][o] in regs ----
    float acck[KN], accv[KN];
    {
        const float b0 = bk[o], b1 = bv[o];
        #pragma unroll
        for (int kk = 0; kk < KN; ++kk) { acck[kk] = b0; accv[kk] = b1; }
        const float4* wk4 = reinterpret_cast<const float4*>(Wk + (long)o * KDIM);
        const float4* wv4 = reinterpret_cast<const float4*>(Wv + (long)o * KDIM);
        for (int g = 0; g < KDIM / 4; ++g) {
            float4 a = wk4[g], c = wv4[g];
            #pragma unroll
            for (int kk = 0; kk < KN; ++kk) {
                float4 x = *reinterpret_cast<const float4*>(&kin[kk][g * 4]);
                acck[kk] += a.x * x.x + a.y * x.y + a.z * x.z + a.w * x.w;
                accv[kk] += c.x * x.x + c.y * x.y + c.z * x.z + c.w * x.w;
            }
        }
    }

    // ---- scores: per-thread partial q[o]*k[kk][o], butterfly over wave ----
    float part[KN];
    #pragma unroll
    for (int kk = 0; kk < KN; ++kk) part[kk] = q_o * acck[kk];
    #pragma unroll
    for (int kk = 0; kk < KN; ++kk) {
        #pragma unroll
        for (int m = 32; m >= 1; m >>= 1)
            part[kk] += __shfl_xor(part[kk], m, 64);
    }
    const int w = tid >> 6;          // wave id; head = w >> 1, partner = w ^ 1
    if ((tid & 63) == 0) {
        #pragma unroll
        for (int kk = 0; kk < KN; ++kk) s->part[w][kk] = part[kk];
    }
    __syncthreads();

    // ---- softmax (redundant per-thread, registers) + attn @ V ----
    {
        float attn[KN];
        float mx = -INFINITY;
        #pragma unroll
        for (int kk = 0; kk < KN; ++kk) {
            float x = (part[kk] + s->part[w ^ 1][kk]) * 0.08838834764831845f;
            if (maskbits & (1u << kk)) x = -1e9f;
            attn[kk] = x;
            mx = fmaxf(mx, x);
        }
        float sum = 0.f;
        #pragma unroll
        for (int kk = 0; kk < KN; ++kk) { attn[kk] = __expf(attn[kk] - mx); sum += attn[kk]; }
        const float inv = 1.f / sum;
        float acc = 0.f;
        #pragma unroll
        for (int kk = 0; kk < KN; ++kk) acc += attn[kk] * accv[kk];
        s->att[o] = acc * inv;
    }
    __syncthreads();

    // ---- Wo projection; zero rows with no valid neighbor ----
    {
        float acc = bo[o] + dot4(Wo + (long)o * QDIM, s->att, QDIM);
        s->o[o] = invalid ? 0.f : acc;
    }
    __syncthreads();

    // ---- MergeLayer: fc2(relu(fc1([attn_out || src_feat]))) ----
    if (tid < DD) {
        const float* r = f1w + (long)tid * (QDIM + DD);
        float acc = f1b[tid] + dot4(r, s->o, QDIM) + dot4(r + QDIM, qin, DD);
        s->h1[tid] = fmaxf(acc, 0.f);
    }
    __syncthreads();
    if (tid < DD) {
        out[tid] = f2b[tid] + dot4(f2w + (long)tid * DD, s->h1, DD);
    }
    __syncthreads();
}

__global__ __launch_bounds__(BLK, 4) void tgn_fused(
    const int* __restrict__ source_nodes, const float* __restrict__ timestamps,
    const int* __restrict__ nbr2, const int* __restrict__ eid2, const float* __restrict__ et2,
    const int* __restrict__ nbr1, const int* __restrict__ eid1, const float* __restrict__ et1,
    const float* __restrict__ nf, const float* __restrict__ mem, const float* __restrict__ ef,
    const float* __restrict__ tw, const float* __restrict__ tb,
    const float* __restrict__ Wq, const float* __restrict__ bq,
    const float* __restrict__ Wk, const float* __restrict__ bk,
    const float* __restrict__ Wv, const float* __restrict__ bv,
    const float* __restrict__ Wo, const float* __restrict__ bo,
    const float* __restrict__ f1w, const float* __restrict__ f1b,
    const float* __restrict__ f2w, const float* __restrict__ f2b,
    float* __restrict__ out)
{
    __shared__ __align__(16) float s_qin[QDIM];
    __shared__ __align__(16) float s_kin[KN][KDIM];
    __shared__ __align__(16) float s_emb[KN][DD];   // hop-2 results
    __shared__ __align__(16) float s_out[DD];
    __shared__ __align__(16) float s_st[TT];        // cos(time_b) (src dt = 0)
    __shared__ Scratch s;
    __shared__ unsigned s_mask;
    __shared__ int s_inv;

    const int b = blockIdx.x, tid = threadIdx.x;
    const float t_src = timestamps[b];   // ts2 = repeat(timestamps, K)

    if (tid < TT) s_st[tid] = __cosf(tb[tid]);
    __syncthreads();

    // ================= hop-2 rows (layer 0) =================
    for (int k = 0; k < KN; ++k) {
        const int row = b * KN + k;
        const int src = nbr2[row];
        if (tid < DD) s_qin[tid] = nf[(long)src * DD + tid] + mem[(long)src * DD + tid];
        else          s_qin[tid] = s_st[tid - DD];
        if (tid == 0) {
            unsigned m = 0;
            for (int kk = 0; kk < KN; ++kk)
                if (nbr1[row * KN + kk] == 0) m |= (1u << kk);
            int inv = (m == ((1u << KN) - 1));
            if (inv) m &= ~(1u << (KN - 1));
            s_mask = m; s_inv = inv;
        }
        for (int w = tid; w < KN * (KDIM / 4); w += BLK) {
            const int kk = w / (KDIM / 4);
            const int e  = (w % (KDIM / 4)) * 4;
            float4 val;
            if (e < DD) {
                const long nb = nbr1[row * KN + kk];
                const float4 a = *(const float4*)&nf[nb * DD + e];
                const float4 c = *(const float4*)&mem[nb * DD + e];
                val = make_float4(a.x + c.x, a.y + c.y, a.z + c.z, a.w + c.w);
            } else if (e < 2 * DD) {
                const long eid = eid1[row * KN + kk];
                val = *(const float4*)&ef[eid * DD + (e - DD)];
            } else {
                const int t = e - 2 * DD;
                const float dt = t_src - et1[row * KN + kk];
                val = make_float4(__cosf(dt * tw[t]     + tb[t]),
                                  __cosf(dt * tw[t + 1] + tb[t + 1]),
                                  __cosf(dt * tw[t + 2] + tb[t + 2]),
                                  __cosf(dt * tw[t + 3] + tb[t + 3]));
            }
            *(float4*)&s_kin[kk][e] = val;
        }
        __syncthreads();
        attn_row(tid, s_qin, s_kin, s_mask, s_inv,
                 Wq, bq, Wk, bk, Wv, bv, Wo, bo, f1w, f1b, f2w, f2b,
                 &s, s_emb[k]);
    }

    // ================= top row (layer 1) =================
    {
        const int src = source_nodes[b];
        if (tid < DD) s_qin[tid] = nf[(long)src * DD + tid] + mem[(long)src * DD + tid];
        else          s_qin[tid] = s_st[tid - DD];
        if (tid == 0) {
            unsigned m = 0;
            for (int kk = 0; kk < KN; ++kk)
                if (nbr2[b * KN + kk] == 0) m |= (1u << kk);
            int inv = (m == ((1u << KN) - 1));
            if (inv) m &= ~(1u << (KN - 1));
            s_mask = m; s_inv = inv;
        }
        for (int w = tid; w < KN * (KDIM / 4); w += BLK) {
            const int kk = w / (KDIM / 4);
            const int e  = (w % (KDIM / 4)) * 4;
            float4 val;
            if (e < DD) {
                val = *(const float4*)&s_emb[kk][e];
            } else if (e < 2 * DD) {
                const long eid = eid2[b * KN + kk];
                val = *(const float4*)&ef[eid * DD + (e - DD)];
            } else {
                const int t = e - 2 * DD;
                const float dt = t_src - et2[b * KN + kk];
                val = make_float4(__cosf(dt * tw[t]     + tb[t]),
                                  __cosf(dt * tw[t + 1] + tb[t + 1]),
                                  __cosf(dt * tw[t + 2] + tb[t + 2]),
                                  __cosf(dt * tw[t + 3] + tb[t + 3]));
            }
            *(float4*)&s_kin[kk][e] = val;
        }
        __syncthreads();
        attn_row(tid, s_qin, s_kin, s_mask, s_inv,
                 Wq + QDIM * QDIM, bq + QDIM,
                 Wk + QDIM * KDIM, bk + QDIM,
                 Wv + QDIM * KDIM, bv + QDIM,
                 Wo + QDIM * QDIM, bo + QDIM,
                 f1w + DD * (QDIM + DD), f1b + DD,
                 f2w + DD * DD, f2b + DD,
                 &s, s_out);
        if (tid < DD) out[(long)b * DD + tid] = s_out[tid];
    }
}

extern "C" void kernel_launch(void* const* d_in, const int* in_sizes, int n_in,
                              void* d_out, int out_size, void* d_ws, size_t ws_size,
                              hipStream_t stream) {
    const float* nf  = (const float*)d_in[0];
    const float* mem = (const float*)d_in[1];
    const float* ef  = (const float*)d_in[2];
    const float* tw  = (const float*)d_in[3];
    const float* tb  = (const float*)d_in[4];
    const float* Wq  = (const float*)d_in[5];
    const float* bq  = (const float*)d_in[6];
    const float* Wk  = (const float*)d_in[7];
    const float* bk  = (const float*)d_in[8];
    const float* Wv  = (const float*)d_in[9];
    const float* bv  = (const float*)d_in[10];
    const float* Wo  = (const float*)d_in[11];
    const float* bo  = (const float*)d_in[12];
    const float* f1w = (const float*)d_in[13];
    const float* f1b = (const float*)d_in[14];
    const float* f2w = (const float*)d_in[15];
    const float* f2b = (const float*)d_in[16];
    const int* src_nodes = (const int*)d_in[17];
    const float* ts  = (const float*)d_in[18];
    const int* nbr2  = (const int*)d_in[19];
    const int* eid2  = (const int*)d_in[20];
    const float* et2 = (const float*)d_in[21];
    const int* nbr1  = (const int*)d_in[22];
    const int* eid1  = (const int*)d_in[23];
    const float* et1 = (const float*)d_in[24];

    const int B = in_sizes[17];   // 2048

    tgn_fused<<<B, BLK, 0, stream>>>(
        src_nodes, ts, nbr2, eid2, et2, nbr1, eid1, et1,
        nf, mem, ef, tw, tb,
        Wq, bq, Wk, bk, Wv, bv, Wo, bo,
        f1w, f1b, f2w, f2b,
        (float*)d_out);
}

// Round 3
// 8745.261 us; speedup vs baseline: 1.5153x; 1.5153x over previous
//
#include <hip/hip_runtime.h>

// Problem constants (from reference)
#define DD   128   // D
#define TT   128   // T
#define QDIM 256   // D + T
#define KDIM 384   // 2D + T
#define KN   10    // K neighbors
#define NH   2     // heads
#define HDIM 128   // QDIM / NH
#define BLK  256

// k/v/scores/softmax live in registers; only cross-thread data in LDS.
struct Scratch {
    float att[QDIM];     // attn @ V result (per output element)
    float o[QDIM];       // Wo projection result
    float h1[DD];        // fc1 hidden
    float part[4][KN];   // per-wave score partial sums
};

__device__ __forceinline__ float dot4(const float* __restrict__ w,
                                      const float* __restrict__ x, int len) {
    const float4* w4 = reinterpret_cast<const float4*>(w);
    const float4* x4 = reinterpret_cast<const float4*>(x);
    float acc = 0.f;
    for (int g = 0; g < len / 4; ++g) {
        float4 a = w4[g], b = x4[g];
        acc += a.x * b.x + a.y * b.y + a.z * b.z + a.w * b.w;
    }
    return acc;
}

// One temporal-attention row. qin [QDIM] and kin [KN][KDIM] must be fully
// built in LDS and covered by a __syncthreads() BEFORE the call. Ends with
// __syncthreads(); result (DD floats) in out (LDS). Weight pointers must be
// pre-offset to the layer slice.
__device__ void attn_row(int tid,
                         const float* __restrict__ qin,
                         const float (* __restrict__ kin)[KDIM],
                         unsigned maskbits, int invalid,
                         const float* __restrict__ Wq, const float* __restrict__ bq,
                         const float* __restrict__ Wk, const float* __restrict__ bk,
                         const float* __restrict__ Wv, const float* __restrict__ bv,
                         const float* __restrict__ Wo, const float* __restrict__ bo,
                         const float* __restrict__ f1w, const float* __restrict__ f1b,
                         const float* __restrict__ f2w, const float* __restrict__ f2b,
                         Scratch* __restrict__ s,
                         float* __restrict__ out)
{
    const int o = tid;

    // ---- K/V projections: thread o computes k[kk][o], v[kk][o] in regs ----
    float acck[KN], accv[KN];
    {
        const float b0 = bk[o], b1 = bv[o];
        #pragma unroll
        for (int kk = 0; kk < KN; ++kk) { acck[kk] = b0; accv[kk] = b1; }
        const float4* wk4 = reinterpret_cast<const float4*>(Wk + (long)o * KDIM);
        const float4* wv4 = reinterpret_cast<const float4*>(Wv + (long)o * KDIM);
        for (int g = 0; g < KDIM / 4; ++g) {
            float4 a = wk4[g], c = wv4[g];
            #pragma unroll
            for (int kk = 0; kk < KN; ++kk) {
                float4 x = *reinterpret_cast<const float4*>(&kin[kk][g * 4]);
                acck[kk] += a.x * x.x + a.y * x.y + a.z * x.z + a.w * x.w;
                accv[kk] += c.x * x.x + c.y * x.y + c.z * x.z + c.w * x.w;
            }
        }
    }

    // ---- Q projection (own output element only; short live range) ----
    const float q_o = bq[o] + dot4(Wq + (long)o * QDIM, qin, QDIM);

    // ---- scores: per-thread partial q[o]*k[kk][o], butterfly over wave.
    //      acck[] is reused in place for the reduced partials. ----
    #pragma unroll
    for (int kk = 0; kk < KN; ++kk) {
        float p = q_o * acck[kk];
        #pragma unroll
        for (int m = 32; m >= 1; m >>= 1)
            p += __shfl_xor(p, m, 64);
        acck[kk] = p;
    }
    const int w = tid >> 6;          // wave id; head = w >> 1, partner = w ^ 1
    if ((tid & 63) == 0) {
        #pragma unroll
        for (int kk = 0; kk < KN; ++kk) s->part[w][kk] = acck[kk];
    }
    __syncthreads();

    // ---- softmax (redundant per-thread, registers) + attn @ V ----
    {
        float mx = -INFINITY;
        #pragma unroll
        for (int kk = 0; kk < KN; ++kk) {
            float x = (acck[kk] + s->part[w ^ 1][kk]) * 0.08838834764831845f;
            if (maskbits & (1u << kk)) x = -1e9f;
            acck[kk] = x;
            mx = fmaxf(mx, x);
        }
        float sum = 0.f;
        #pragma unroll
        for (int kk = 0; kk < KN; ++kk) { acck[kk] = __expf(acck[kk] - mx); sum += acck[kk]; }
        const float inv = 1.f / sum;
        float acc = 0.f;
        #pragma unroll
        for (int kk = 0; kk < KN; ++kk) acc += acck[kk] * accv[kk];
        s->att[o] = acc * inv;
    }
    __syncthreads();

    // ---- Wo projection; zero rows with no valid neighbor ----
    {
        float acc = bo[o] + dot4(Wo + (long)o * QDIM, s->att, QDIM);
        s->o[o] = invalid ? 0.f : acc;
    }
    __syncthreads();

    // ---- MergeLayer: fc2(relu(fc1([attn_out || src_feat]))) ----
    if (tid < DD) {
        const float* r = f1w + (long)tid * (QDIM + DD);
        float acc = f1b[tid] + dot4(r, s->o, QDIM) + dot4(r + QDIM, qin, DD);
        s->h1[tid] = fmaxf(acc, 0.f);
    }
    __syncthreads();
    if (tid < DD) {
        out[tid] = f2b[tid] + dot4(f2w + (long)tid * DD, s->h1, DD);
    }
    __syncthreads();
}

__global__ __launch_bounds__(BLK) void tgn_fused(
    const int* __restrict__ source_nodes, const float* __restrict__ timestamps,
    const int* __restrict__ nbr2, const int* __restrict__ eid2, const float* __restrict__ et2,
    const int* __restrict__ nbr1, const int* __restrict__ eid1, const float* __restrict__ et1,
    const float* __restrict__ nf, const float* __restrict__ mem, const float* __restrict__ ef,
    const float* __restrict__ tw, const float* __restrict__ tb,
    const float* __restrict__ Wq, const float* __restrict__ bq,
    const float* __restrict__ Wk, const float* __restrict__ bk,
    const float* __restrict__ Wv, const float* __restrict__ bv,
    const float* __restrict__ Wo, const float* __restrict__ bo,
    const float* __restrict__ f1w, const float* __restrict__ f1b,
    const float* __restrict__ f2w, const float* __restrict__ f2b,
    float* __restrict__ out)
{
    __shared__ __align__(16) float s_qin[QDIM];
    __shared__ __align__(16) float s_kin[KN][KDIM];
    __shared__ __align__(16) float s_emb[KN][DD];   // hop-2 results
    __shared__ __align__(16) float s_out[DD];
    __shared__ __align__(16) float s_st[TT];        // cos(time_b) (src dt = 0)
    __shared__ Scratch s;
    __shared__ unsigned s_mask;
    __shared__ int s_inv;

    const int b = blockIdx.x, tid = threadIdx.x;
    const float t_src = timestamps[b];   // ts2 = repeat(timestamps, K)

    if (tid < TT) s_st[tid] = __cosf(tb[tid]);
    __syncthreads();

    // ================= hop-2 rows (layer 0) =================
    for (int k = 0; k < KN; ++k) {
        const int row = b * KN + k;
        const int src = nbr2[row];
        if (tid < DD) s_qin[tid] = nf[(long)src * DD + tid] + mem[(long)src * DD + tid];
        else          s_qin[tid] = s_st[tid - DD];
        if (tid == 0) {
            unsigned m = 0;
            for (int kk = 0; kk < KN; ++kk)
                if (nbr1[row * KN + kk] == 0) m |= (1u << kk);
            int inv = (m == ((1u << KN) - 1));
            if (inv) m &= ~(1u << (KN - 1));
            s_mask = m; s_inv = inv;
        }
        for (int w = tid; w < KN * (KDIM / 4); w += BLK) {
            const int kk = w / (KDIM / 4);
            const int e  = (w % (KDIM / 4)) * 4;
            float4 val;
            if (e < DD) {
                const long nb = nbr1[row * KN + kk];
                const float4 a = *(const float4*)&nf[nb * DD + e];
                const float4 c = *(const float4*)&mem[nb * DD + e];
                val = make_float4(a.x + c.x, a.y + c.y, a.z + c.z, a.w + c.w);
            } else if (e < 2 * DD) {
                const long eid = eid1[row * KN + kk];
                val = *(const float4*)&ef[eid * DD + (e - DD)];
            } else {
                const int t = e - 2 * DD;
                const float dt = t_src - et1[row * KN + kk];
                val = make_float4(__cosf(dt * tw[t]     + tb[t]),
                                  __cosf(dt * tw[t + 1] + tb[t + 1]),
                                  __cosf(dt * tw[t + 2] + tb[t + 2]),
                                  __cosf(dt * tw[t + 3] + tb[t + 3]));
            }
            *(float4*)&s_kin[kk][e] = val;
        }
        __syncthreads();
        attn_row(tid, s_qin, s_kin, s_mask, s_inv,
                 Wq, bq, Wk, bk, Wv, bv, Wo, bo, f1w, f1b, f2w, f2b,
                 &s, s_emb[k]);
    }

    // ================= top row (layer 1) =================
    {
        const int src = source_nodes[b];
        if (tid < DD) s_qin[tid] = nf[(long)src * DD + tid] + mem[(long)src * DD + tid];
        else          s_qin[tid] = s_st[tid - DD];
        if (tid == 0) {
            unsigned m = 0;
            for (int kk = 0; kk < KN; ++kk)
                if (nbr2[b * KN + kk] == 0) m |= (1u << kk);
            int inv = (m == ((1u << KN) - 1));
            if (inv) m &= ~(1u << (KN - 1));
            s_mask = m; s_inv = inv;
        }
        for (int w = tid; w < KN * (KDIM / 4); w += BLK) {
            const int kk = w / (KDIM / 4);
            const int e  = (w % (KDIM / 4)) * 4;
            float4 val;
            if (e < DD) {
                val = *(const float4*)&s_emb[kk][e];
            } else if (e < 2 * DD) {
                const long eid = eid2[b * KN + kk];
                val = *(const float4*)&ef[eid * DD + (e - DD)];
            } else {
                const int t = e - 2 * DD;
                const float dt = t_src - et2[b * KN + kk];
                val = make_float4(__cosf(dt * tw[t]     + tb[t]),
                                  __cosf(dt * tw[t + 1] + tb[t + 1]),
                                  __cosf(dt * tw[t + 2] + tb[t + 2]),
                                  __cosf(dt * tw[t + 3] + tb[t + 3]));
            }
            *(float4*)&s_kin[kk][e] = val;
        }
        __syncthreads();
        attn_row(tid, s_qin, s_kin, s_mask, s_inv,
                 Wq + QDIM * QDIM, bq + QDIM,
                 Wk + QDIM * KDIM, bk + QDIM,
                 Wv + QDIM * KDIM, bv + QDIM,
                 Wo + QDIM * QDIM, bo + QDIM,
                 f1w + DD * (QDIM + DD), f1b + DD,
                 f2w + DD * DD, f2b + DD,
                 &s, s_out);
        if (tid < DD) out[(long)b * DD + tid] = s_out[tid];
    }
}

extern "C" void kernel_launch(void* const* d_in, const int* in_sizes, int n_in,
                              void* d_out, int out_size, void* d_ws, size_t ws_size,
                              hipStream_t stream) {
    const float* nf  = (const float*)d_in[0];
    const float* mem = (const float*)d_in[1];
    const float* ef  = (const float*)d_in[2];
    const float* tw  = (const float*)d_in[3];
    const float* tb  = (const float*)d_in[4];
    const float* Wq  = (const float*)d_in[5];
    const float* bq  = (const float*)d_in[6];
    const float* Wk  = (const float*)d_in[7];
    const float* bk  = (const float*)d_in[8];
    const float* Wv  = (const float*)d_in[9];
    const float* bv  = (const float*)d_in[10];
    const float* Wo  = (const float*)d_in[11];
    const float* bo  = (const float*)d_in[12];
    const float* f1w = (const float*)d_in[13];
    const float* f1b = (const float*)d_in[14];
    const float* f2w = (const float*)d_in[15];
    const float* f2b = (const float*)d_in[16];
    const int* src_nodes = (const int*)d_in[17];
    const float* ts  = (const float*)d_in[18];
    const int* nbr2  = (const int*)d_in[19];
    const int* eid2  = (const int*)d_in[20];
    const float* et2 = (const float*)d_in[21];
    const int* nbr1  = (const int*)d_in[22];
    const int* eid1  = (const int*)d_in[23];
    const float* et1 = (const float*)d_in[24];

    const int B = in_sizes[17];   // 2048

    tgn_fused<<<B, BLK, 0, stream>>>(
        src_nodes, ts, nbr2, eid2, et2, nbr1, eid1, et1,
        nf, mem, ef, tw, tb,
        Wq, bq, Wk, bk, Wv, bv, Wo, bo,
        f1w, f1b, f2w, f2b,
        (float*)d_out);
}

// Round 4
// 6501.824 us; speedup vs baseline: 2.0381x; 1.3450x over previous
//
#include <hip/hip_runtime.h>

// Problem constants (from reference)
#define DD   128   // D
#define TT   128   // T
#define QDIM 256   // D + T
#define KDIM 384   // 2D + T
#define KN   10    // K neighbors
#define NH   2     // heads
#define HDIM 128   // QDIM / NH
#define BLK  256

// k/v/scores/softmax live in registers; only cross-thread data in LDS.
struct Scratch {
    float att[QDIM];     // attn @ V result (per output element)
    float o[QDIM];       // Wo projection result
    float h1[DD];        // fc1 hidden
    float part[4][KN];   // per-wave score partial sums
};

// Dot product with explicit 1-ahead weight prefetch (w streams from global,
// x is LDS). Keeping the next iteration's load in flight needs VGPR headroom
// — see __launch_bounds__ note at the kernel.
__device__ __forceinline__ float dotp(const float* __restrict__ w,
                                      const float* __restrict__ x, int len) {
    const float4* w4 = reinterpret_cast<const float4*>(w);
    const float4* x4 = reinterpret_cast<const float4*>(x);
    const int n = len / 4;
    float4 a0 = w4[0];
    float acc = 0.f;
    #pragma unroll 4
    for (int g = 0; g < n; ++g) {
        const float4 a = a0;
        if (g + 1 < n) a0 = w4[g + 1];
        const float4 b = x4[g];
        acc += a.x * b.x + a.y * b.y + a.z * b.z + a.w * b.w;
    }
    return acc;
}

// One temporal-attention row. qin [QDIM] and kin [KN][KDIM] must be fully
// built in LDS and covered by a __syncthreads() BEFORE the call. Ends with
// __syncthreads(); result (DD floats) in out (LDS). Weight pointers must be
// pre-offset to the layer slice.
__device__ void attn_row(int tid,
                         const float* __restrict__ qin,
                         const float (* __restrict__ kin)[KDIM],
                         unsigned maskbits, int invalid,
                         const float* __restrict__ Wq, const float* __restrict__ bq,
                         const float* __restrict__ Wk, const float* __restrict__ bk,
                         const float* __restrict__ Wv, const float* __restrict__ bv,
                         const float* __restrict__ Wo, const float* __restrict__ bo,
                         const float* __restrict__ f1w, const float* __restrict__ f1b,
                         const float* __restrict__ f2w, const float* __restrict__ f2b,
                         Scratch* __restrict__ s,
                         float* __restrict__ out)
{
    const int o = tid;

    // ---- K/V projections: thread o computes k[kk][o], v[kk][o] in regs.
    //      2-deep software pipeline on the weight stream: loads for g+1/g+2
    //      stay in flight while the 80 FMAs of iteration g execute. ----
    float acck[KN], accv[KN];
    {
        const float b0 = bk[o], b1 = bv[o];
        #pragma unroll
        for (int kk = 0; kk < KN; ++kk) { acck[kk] = b0; accv[kk] = b1; }
        const float4* wk4 = reinterpret_cast<const float4*>(Wk + (long)o * KDIM);
        const float4* wv4 = reinterpret_cast<const float4*>(Wv + (long)o * KDIM);
        const int n = KDIM / 4;                 // 96
        float4 wa0 = wk4[0], wc0 = wv4[0];
        float4 wa1 = wk4[1], wc1 = wv4[1];
        #pragma unroll 2
        for (int g = 0; g < n; ++g) {
            const float4 a = wa0, c = wc0;
            wa0 = wa1; wc0 = wc1;
            if (g + 2 < n) { wa1 = wk4[g + 2]; wc1 = wv4[g + 2]; }
            #pragma unroll
            for (int kk = 0; kk < KN; ++kk) {
                const float4 x = *reinterpret_cast<const float4*>(&kin[kk][g * 4]);
                acck[kk] += a.x * x.x + a.y * x.y + a.z * x.z + a.w * x.w;
                accv[kk] += c.x * x.x + c.y * x.y + c.z * x.z + c.w * x.w;
            }
        }
    }

    // ---- Q projection (own output element only; short live range) ----
    const float q_o = bq[o] + dotp(Wq + (long)o * QDIM, qin, QDIM);

    // ---- scores: per-thread partial q[o]*k[kk][o], butterfly over wave.
    //      acck[] is reused in place for the reduced partials. ----
    #pragma unroll
    for (int kk = 0; kk < KN; ++kk) {
        float p = q_o * acck[kk];
        #pragma unroll
        for (int m = 32; m >= 1; m >>= 1)
            p += __shfl_xor(p, m, 64);
        acck[kk] = p;
    }
    const int w = tid >> 6;          // wave id; head = w >> 1, partner = w ^ 1
    if ((tid & 63) == 0) {
        #pragma unroll
        for (int kk = 0; kk < KN; ++kk) s->part[w][kk] = acck[kk];
    }
    __syncthreads();

    // ---- softmax (redundant per-thread, registers) + attn @ V ----
    {
        float mx = -INFINITY;
        #pragma unroll
        for (int kk = 0; kk < KN; ++kk) {
            float x = (acck[kk] + s->part[w ^ 1][kk]) * 0.08838834764831845f;
            if (maskbits & (1u << kk)) x = -1e9f;
            acck[kk] = x;
            mx = fmaxf(mx, x);
        }
        float sum = 0.f;
        #pragma unroll
        for (int kk = 0; kk < KN; ++kk) { acck[kk] = __expf(acck[kk] - mx); sum += acck[kk]; }
        const float inv = 1.f / sum;
        float acc = 0.f;
        #pragma unroll
        for (int kk = 0; kk < KN; ++kk) acc += acck[kk] * accv[kk];
        s->att[o] = acc * inv;
    }
    __syncthreads();

    // ---- Wo projection; zero rows with no valid neighbor ----
    {
        float acc = bo[o] + dotp(Wo + (long)o * QDIM, s->att, QDIM);
        s->o[o] = invalid ? 0.f : acc;
    }
    __syncthreads();

    // ---- MergeLayer: fc2(relu(fc1([attn_out || src_feat]))) ----
    if (tid < DD) {
        const float* r = f1w + (long)tid * (QDIM + DD);
        float acc = f1b[tid] + dotp(r, s->o, QDIM) + dotp(r + QDIM, qin, DD);
        s->h1[tid] = fmaxf(acc, 0.f);
    }
    __syncthreads();
    if (tid < DD) {
        out[tid] = f2b[tid] + dotp(f2w + (long)tid * DD, s->h1, DD);
    }
    __syncthreads();
}

// min 2 blocks/CU (2nd arg = min waves/EU; for 256-thread blocks this equals
// blocks/CU). Caps VGPR at 256 — enough headroom for the software pipeline,
// without the round-1 mistake of forcing 64-VGPR spills.
__global__ __launch_bounds__(BLK, 2) void tgn_fused(
    const int* __restrict__ source_nodes, const float* __restrict__ timestamps,
    const int* __restrict__ nbr2, const int* __restrict__ eid2, const float* __restrict__ et2,
    const int* __restrict__ nbr1, const int* __restrict__ eid1, const float* __restrict__ et1,
    const float* __restrict__ nf, const float* __restrict__ mem, const float* __restrict__ ef,
    const float* __restrict__ tw, const float* __restrict__ tb,
    const float* __restrict__ Wq, const float* __restrict__ bq,
    const float* __restrict__ Wk, const float* __restrict__ bk,
    const float* __restrict__ Wv, const float* __restrict__ bv,
    const float* __restrict__ Wo, const float* __restrict__ bo,
    const float* __restrict__ f1w, const float* __restrict__ f1b,
    const float* __restrict__ f2w, const float* __restrict__ f2b,
    float* __restrict__ out)
{
    __shared__ __align__(16) float s_qin[QDIM];
    __shared__ __align__(16) float s_kin[KN][KDIM];
    __shared__ __align__(16) float s_emb[KN][DD];   // hop-2 results
    __shared__ __align__(16) float s_out[DD];
    __shared__ __align__(16) float s_st[TT];        // cos(time_b) (src dt = 0)
    __shared__ Scratch s;
    __shared__ unsigned s_mask;
    __shared__ int s_inv;

    const int b = blockIdx.x, tid = threadIdx.x;
    const float t_src = timestamps[b];   // ts2 = repeat(timestamps, K)

    if (tid < TT) s_st[tid] = __cosf(tb[tid]);
    __syncthreads();

    // ================= hop-2 rows (layer 0) =================
    for (int k = 0; k < KN; ++k) {
        const int row = b * KN + k;
        const int src = nbr2[row];
        if (tid < DD) s_qin[tid] = nf[(long)src * DD + tid] + mem[(long)src * DD + tid];
        else          s_qin[tid] = s_st[tid - DD];
        if (tid == 0) {
            unsigned m = 0;
            for (int kk = 0; kk < KN; ++kk)
                if (nbr1[row * KN + kk] == 0) m |= (1u << kk);
            int inv = (m == ((1u << KN) - 1));
            if (inv) m &= ~(1u << (KN - 1));
            s_mask = m; s_inv = inv;
        }
        for (int w = tid; w < KN * (KDIM / 4); w += BLK) {
            const int kk = w / (KDIM / 4);
            const int e  = (w % (KDIM / 4)) * 4;
            float4 val;
            if (e < DD) {
                const long nb = nbr1[row * KN + kk];
                const float4 a = *(const float4*)&nf[nb * DD + e];
                const float4 c = *(const float4*)&mem[nb * DD + e];
                val = make_float4(a.x + c.x, a.y + c.y, a.z + c.z, a.w + c.w);
            } else if (e < 2 * DD) {
                const long eid = eid1[row * KN + kk];
                val = *(const float4*)&ef[eid * DD + (e - DD)];
            } else {
                const int t = e - 2 * DD;
                const float dt = t_src - et1[row * KN + kk];
                val = make_float4(__cosf(dt * tw[t]     + tb[t]),
                                  __cosf(dt * tw[t + 1] + tb[t + 1]),
                                  __cosf(dt * tw[t + 2] + tb[t + 2]),
                                  __cosf(dt * tw[t + 3] + tb[t + 3]));
            }
            *(float4*)&s_kin[kk][e] = val;
        }
        __syncthreads();
        attn_row(tid, s_qin, s_kin, s_mask, s_inv,
                 Wq, bq, Wk, bk, Wv, bv, Wo, bo, f1w, f1b, f2w, f2b,
                 &s, s_emb[k]);
    }

    // ================= top row (layer 1) =================
    {
        const int src = source_nodes[b];
        if (tid < DD) s_qin[tid] = nf[(long)src * DD + tid] + mem[(long)src * DD + tid];
        else          s_qin[tid] = s_st[tid - DD];
        if (tid == 0) {
            unsigned m = 0;
            for (int kk = 0; kk < KN; ++kk)
                if (nbr2[b * KN + kk] == 0) m |= (1u << kk);
            int inv = (m == ((1u << KN) - 1));
            if (inv) m &= ~(1u << (KN - 1));
            s_mask = m; s_inv = inv;
        }
        for (int w = tid; w < KN * (KDIM / 4); w += BLK) {
            const int kk = w / (KDIM / 4);
            const int e  = (w % (KDIM / 4)) * 4;
            float4 val;
            if (e < DD) {
                val = *(const float4*)&s_emb[kk][e];
            } else if (e < 2 * DD) {
                const long eid = eid2[b * KN + kk];
                val = *(const float4*)&ef[eid * DD + (e - DD)];
            } else {
                const int t = e - 2 * DD;
                const float dt = t_src - et2[b * KN + kk];
                val = make_float4(__cosf(dt * tw[t]     + tb[t]),
                                  __cosf(dt * tw[t + 1] + tb[t + 1]),
                                  __cosf(dt * tw[t + 2] + tb[t + 2]),
                                  __cosf(dt * tw[t + 3] + tb[t + 3]));
            }
            *(float4*)&s_kin[kk][e] = val;
        }
        __syncthreads();
        attn_row(tid, s_qin, s_kin, s_mask, s_inv,
                 Wq + QDIM * QDIM, bq + QDIM,
                 Wk + QDIM * KDIM, bk + QDIM,
                 Wv + QDIM * KDIM, bv + QDIM,
                 Wo + QDIM * QDIM, bo + QDIM,
                 f1w + DD * (QDIM + DD), f1b + DD,
                 f2w + DD * DD, f2b + DD,
                 &s, s_out);
        if (tid < DD) out[(long)b * DD + tid] = s_out[tid];
    }
}

extern "C" void kernel_launch(void* const* d_in, const int* in_sizes, int n_in,
                              void* d_out, int out_size, void* d_ws, size_t ws_size,
                              hipStream_t stream) {
    const float* nf  = (const float*)d_in[0];
    const float* mem = (const float*)d_in[1];
    const float* ef  = (const float*)d_in[2];
    const float* tw  = (const float*)d_in[3];
    const float* tb  = (const float*)d_in[4];
    const float* Wq  = (const float*)d_in[5];
    const float* bq  = (const float*)d_in[6];
    const float* Wk  = (const float*)d_in[7];
    const float* bk  = (const float*)d_in[8];
    const float* Wv  = (const float*)d_in[9];
    const float* bv  = (const float*)d_in[10];
    const float* Wo  = (const float*)d_in[11];
    const float* bo  = (const float*)d_in[12];
    const float* f1w = (const float*)d_in[13];
    const float* f1b = (const float*)d_in[14];
    const float* f2w = (const float*)d_in[15];
    const float* f2b = (const float*)d_in[16];
    const int* src_nodes = (const int*)d_in[17];
    const float* ts  = (const float*)d_in[18];
    const int* nbr2  = (const int*)d_in[19];
    const int* eid2  = (const int*)d_in[20];
    const float* et2 = (const float*)d_in[21];
    const int* nbr1  = (const int*)d_in[22];
    const int* eid1  = (const int*)d_in[23];
    const float* et1 = (const float*)d_in[24];

    const int B = in_sizes[17];   // 2048

    tgn_fused<<<B, BLK, 0, stream>>>(
        src_nodes, ts, nbr2, eid2, et2, nbr1, eid1, et1,
        nf, mem, ef, tw, tb,
        Wq, bq, Wk, bk, Wv, bv, Wo, bo,
        f1w, f1b, f2w, f2b,
        (float*)d_out);
}

// Round 5
// 4409.930 us; speedup vs baseline: 3.0050x; 1.4744x over previous
//
#include <hip/hip_runtime.h>

// Problem constants (from reference)
#define DD   128   // D
#define TT   128   // T
#define QDIM 256   // D + T
#define KDIM 384   // 2D + T
#define KN   10    // K neighbors
#define BLK  256
#define RMAX 4     // rows batched per weight pass

// LDS pool: kin for RMAX rows; post-projection scratch (att/o/h1) overlays
// the same region (kin is dead after the K/V pass; the s_part barrier
// guarantees all waves have finished reading kin before att is written).
#define POOL_FLOATS (RMAX * KN * KDIM)      // 15360 floats = 61.4 KB
#define ATT_OFF 0                           // [RMAX][QDIM]
#define OO_OFF  (RMAX * QDIM)               // [RMAX][QDIM]
#define H1_OFF  (2 * RMAX * QDIM)           // [RMAX][DD]

// One weight pass over RA attention rows. qin [RA][QDIM] and kin (in pool)
// must be staged and barriered BEFORE the call. Ends with __syncthreads().
// Each weight matrix is streamed from global exactly ONCE for all RA rows.
template<int RA>
__device__ void attn_rows(const int tid,
                          const float* __restrict__ qin,
                          float* __restrict__ pool,
                          const unsigned* __restrict__ maskA,
                          const int* __restrict__ invA,
                          float (* __restrict__ part)[RMAX][KN],
                          const float* __restrict__ Wq, const float* __restrict__ bq,
                          const float* __restrict__ Wk, const float* __restrict__ bk,
                          const float* __restrict__ Wv, const float* __restrict__ bv,
                          const float* __restrict__ Wo, const float* __restrict__ bo,
                          const float* __restrict__ f1w, const float* __restrict__ f1b,
                          const float* __restrict__ f2w, const float* __restrict__ f2b,
                          float* __restrict__ dstBase)   // RA rows, stride DD
{
    const int o = tid;

    // ---- K/V projections: thread o accumulates k/v[r][kk][o] in regs ----
    float acck[RA][KN], accv[RA][KN];
    {
        const float b0 = bk[o], b1 = bv[o];
        #pragma unroll
        for (int r = 0; r < RA; ++r)
            #pragma unroll
            for (int kk = 0; kk < KN; ++kk) { acck[r][kk] = b0; accv[r][kk] = b1; }
        const float4* wk4 = reinterpret_cast<const float4*>(Wk + (long)o * KDIM);
        const float4* wv4 = reinterpret_cast<const float4*>(Wv + (long)o * KDIM);
        float4 wa0 = wk4[0], wc0 = wv4[0];
        float4 wa1 = wk4[1], wc1 = wv4[1];
        #pragma unroll 2
        for (int g = 0; g < KDIM / 4; ++g) {
            const float4 a = wa0, c = wc0;
            wa0 = wa1; wc0 = wc1;
            if (g + 2 < KDIM / 4) { wa1 = wk4[g + 2]; wc1 = wv4[g + 2]; }
            #pragma unroll
            for (int r = 0; r < RA; ++r) {
                #pragma unroll
                for (int kk = 0; kk < KN; ++kk) {
                    const float4 x = *reinterpret_cast<const float4*>(
                        &pool[(r * KN + kk) * KDIM + g * 4]);
                    acck[r][kk] += a.x * x.x + a.y * x.y + a.z * x.z + a.w * x.w;
                    accv[r][kk] += c.x * x.x + c.y * x.y + c.z * x.z + c.w * x.w;
                }
            }
        }
    }

    // ---- Q projection (one weight pass for all RA rows) + scores ----
    {
        float qv[RA];
        const float b0 = bq[o];
        #pragma unroll
        for (int r = 0; r < RA; ++r) qv[r] = b0;
        const float4* wq4 = reinterpret_cast<const float4*>(Wq + (long)o * QDIM);
        float4 a0 = wq4[0], a1 = wq4[1];
        #pragma unroll 2
        for (int g = 0; g < QDIM / 4; ++g) {
            const float4 a = a0; a0 = a1;
            if (g + 2 < QDIM / 4) a1 = wq4[g + 2];
            #pragma unroll
            for (int r = 0; r < RA; ++r) {
                const float4 x = *reinterpret_cast<const float4*>(&qin[r * QDIM + g * 4]);
                qv[r] += a.x * x.x + a.y * x.y + a.z * x.z + a.w * x.w;
            }
        }
        // per-thread partial q[o]*k[r][kk][o]; butterfly over the wave
        #pragma unroll
        for (int r = 0; r < RA; ++r) {
            #pragma unroll
            for (int kk = 0; kk < KN; ++kk) {
                float p = qv[r] * acck[r][kk];
                #pragma unroll
                for (int m = 32; m >= 1; m >>= 1) p += __shfl_xor(p, m, 64);
                acck[r][kk] = p;
            }
        }
    }
    const int w = tid >> 6;      // wave id; head = w>>1, partner wave = w^1
    if ((tid & 63) == 0) {
        #pragma unroll
        for (int r = 0; r < RA; ++r)
            #pragma unroll
            for (int kk = 0; kk < KN; ++kk) part[w][r][kk] = acck[r][kk];
    }
    __syncthreads();   // after this barrier all waves are done reading kin

    // ---- softmax (redundant per thread, in regs) + attn @ V ----
    #pragma unroll
    for (int r = 0; r < RA; ++r) {
        const unsigned mb = maskA[r];
        float mx = -INFINITY;
        #pragma unroll
        for (int kk = 0; kk < KN; ++kk) {
            float x = (acck[r][kk] + part[w ^ 1][r][kk]) * 0.08838834764831845f;
            if (mb & (1u << kk)) x = -1e9f;
            acck[r][kk] = x; mx = fmaxf(mx, x);
        }
        float sum = 0.f;
        #pragma unroll
        for (int kk = 0; kk < KN; ++kk) { acck[r][kk] = __expf(acck[r][kk] - mx); sum += acck[r][kk]; }
        const float inv = 1.f / sum;
        float acc = 0.f;
        #pragma unroll
        for (int kk = 0; kk < KN; ++kk) acc += acck[r][kk] * accv[r][kk];
        pool[ATT_OFF + r * QDIM + o] = acc * inv;     // overlays dead kin
    }
    __syncthreads();

    // ---- Wo projection (one weight pass); zero invalid rows ----
    {
        float ov[RA];
        const float b0 = bo[o];
        #pragma unroll
        for (int r = 0; r < RA; ++r) ov[r] = b0;
        const float4* wo4 = reinterpret_cast<const float4*>(Wo + (long)o * QDIM);
        float4 a0 = wo4[0], a1 = wo4[1];
        #pragma unroll 2
        for (int g = 0; g < QDIM / 4; ++g) {
            const float4 a = a0; a0 = a1;
            if (g + 2 < QDIM / 4) a1 = wo4[g + 2];
            #pragma unroll
            for (int r = 0; r < RA; ++r) {
                const float4 x = *reinterpret_cast<const float4*>(
                    &pool[ATT_OFF + r * QDIM + g * 4]);
                ov[r] += a.x * x.x + a.y * x.y + a.z * x.z + a.w * x.w;
            }
        }
        #pragma unroll
        for (int r = 0; r < RA; ++r)
            pool[OO_OFF + r * QDIM + o] = invA[r] ? 0.f : ov[r];
    }
    __syncthreads();

    // ---- MergeLayer fc1: relu(f1w @ [attn_out || src_feat]) ----
    if (tid < DD) {
        float hv[RA];
        const float b0 = f1b[tid];
        #pragma unroll
        for (int r = 0; r < RA; ++r) hv[r] = b0;
        const float4* w1 = reinterpret_cast<const float4*>(f1w + (long)tid * (QDIM + DD));
        float4 a0 = w1[0], a1 = w1[1];
        #pragma unroll 2
        for (int g = 0; g < QDIM / 4; ++g) {        // attn_out part
            const float4 a = a0; a0 = a1;
            if (g + 2 < (QDIM + DD) / 4) a1 = w1[g + 2];
            #pragma unroll
            for (int r = 0; r < RA; ++r) {
                const float4 x = *reinterpret_cast<const float4*>(
                    &pool[OO_OFF + r * QDIM + g * 4]);
                hv[r] += a.x * x.x + a.y * x.y + a.z * x.z + a.w * x.w;
            }
        }
        #pragma unroll 2
        for (int g = QDIM / 4; g < (QDIM + DD) / 4; ++g) {   // src_feat part
            const float4 a = a0; a0 = a1;
            if (g + 2 < (QDIM + DD) / 4) a1 = w1[g + 2];
            #pragma unroll
            for (int r = 0; r < RA; ++r) {
                const float4 x = *reinterpret_cast<const float4*>(
                    &qin[r * QDIM + (g - QDIM / 4) * 4]);
                hv[r] += a.x * x.x + a.y * x.y + a.z * x.z + a.w * x.w;
            }
        }
        #pragma unroll
        for (int r = 0; r < RA; ++r)
            pool[H1_OFF + r * DD + tid] = fmaxf(hv[r], 0.f);
    }
    __syncthreads();

    // ---- fc2 ----
    if (tid < DD) {
        float yv[RA];
        const float b0 = f2b[tid];
        #pragma unroll
        for (int r = 0; r < RA; ++r) yv[r] = b0;
        const float4* w2 = reinterpret_cast<const float4*>(f2w + (long)tid * DD);
        float4 a0 = w2[0], a1 = w2[1];
        #pragma unroll 2
        for (int g = 0; g < DD / 4; ++g) {
            const float4 a = a0; a0 = a1;
            if (g + 2 < DD / 4) a1 = w2[g + 2];
            #pragma unroll
            for (int r = 0; r < RA; ++r) {
                const float4 x = *reinterpret_cast<const float4*>(
                    &pool[H1_OFF + r * DD + g * 4]);
                yv[r] += a.x * x.x + a.y * x.y + a.z * x.z + a.w * x.w;
            }
        }
        #pragma unroll
        for (int r = 0; r < RA; ++r)
            dstBase[r * DD + tid] = yv[r];
    }
    __syncthreads();
}

// Stage qin/masks/kin for RA hop-2 rows starting at `base`. Runtime RA is
// fine here (no register-array indexing).
__device__ void stage_hop2(const int tid, const int b, const int base, const int RA,
                           const float t_src,
                           const int* __restrict__ nbr2,
                           const int* __restrict__ nbr1, const int* __restrict__ eid1,
                           const float* __restrict__ et1,
                           const float* __restrict__ nf, const float* __restrict__ mem,
                           const float* __restrict__ ef,
                           const float* __restrict__ tw, const float* __restrict__ tb,
                           const float* __restrict__ st,
                           float* __restrict__ qin, float* __restrict__ pool,
                           unsigned* __restrict__ maskA, int* __restrict__ invA)
{
    // qin rows (vectorized)
    for (int idx = tid; idx < RA * (QDIM / 4); idx += BLK) {
        const int r = idx >> 6;            // / (QDIM/4)
        const int e = (idx & 63) * 4;
        const int src = nbr2[b * KN + base + r];
        float4 v;
        if (e < DD) {
            const float4 A = *(const float4*)&nf[(long)src * DD + e];
            const float4 C = *(const float4*)&mem[(long)src * DD + e];
            v = make_float4(A.x + C.x, A.y + C.y, A.z + C.z, A.w + C.w);
        } else {
            v = *(const float4*)&st[e - DD];
        }
        *(float4*)&qin[r * QDIM + e] = v;
    }
    // masks
    if (tid < RA) {
        const int row = b * KN + base + tid;
        unsigned m = 0;
        for (int kk = 0; kk < KN; ++kk)
            if (nbr1[row * KN + kk] == 0) m |= (1u << kk);
        int inv = (m == ((1u << KN) - 1));
        if (inv) m &= ~(1u << (KN - 1));
        maskA[tid] = m; invA[tid] = inv;
    }
    // kin rows
    for (int widx = tid; widx < RA * KN * (KDIM / 4); widx += BLK) {
        const int r  = widx / (KN * (KDIM / 4));
        const int t2 = widx - r * (KN * (KDIM / 4));
        const int kk = t2 / (KDIM / 4);
        const int g  = t2 - kk * (KDIM / 4);
        const int e  = g * 4;
        const int row = b * KN + base + r;
        float4 val;
        if (e < DD) {
            const long nb = nbr1[row * KN + kk];
            const float4 A = *(const float4*)&nf[nb * DD + e];
            const float4 C = *(const float4*)&mem[nb * DD + e];
            val = make_float4(A.x + C.x, A.y + C.y, A.z + C.z, A.w + C.w);
        } else if (e < 2 * DD) {
            const long eid = eid1[row * KN + kk];
            val = *(const float4*)&ef[eid * DD + (e - DD)];
        } else {
            const int t = e - 2 * DD;
            const float dt = t_src - et1[row * KN + kk];
            val = make_float4(__cosf(dt * tw[t]     + tb[t]),
                              __cosf(dt * tw[t + 1] + tb[t + 1]),
                              __cosf(dt * tw[t + 2] + tb[t + 2]),
                              __cosf(dt * tw[t + 3] + tb[t + 3]));
        }
        *(float4*)&pool[(r * KN + kk) * KDIM + e] = val;
    }
}

// min 2 blocks/CU: gives the allocator a 256-VGPR budget (acck/accv arrays
// need ~160 live regs with pipelining) without the round-1 spill disaster.
__global__ __launch_bounds__(BLK, 2) void tgn_fused(
    const int* __restrict__ source_nodes, const float* __restrict__ timestamps,
    const int* __restrict__ nbr2, const int* __restrict__ eid2, const float* __restrict__ et2,
    const int* __restrict__ nbr1, const int* __restrict__ eid1, const float* __restrict__ et1,
    const float* __restrict__ nf, const float* __restrict__ mem, const float* __restrict__ ef,
    const float* __restrict__ tw, const float* __restrict__ tb,
    const float* __restrict__ Wq, const float* __restrict__ bq,
    const float* __restrict__ Wk, const float* __restrict__ bk,
    const float* __restrict__ Wv, const float* __restrict__ bv,
    const float* __restrict__ Wo, const float* __restrict__ bo,
    const float* __restrict__ f1w, const float* __restrict__ f1b,
    const float* __restrict__ f2w, const float* __restrict__ f2b,
    float* __restrict__ out)
{
    __shared__ __align__(16) float s_pool[POOL_FLOATS];      // 61.4 KB
    __shared__ __align__(16) float s_qin[RMAX * QDIM];       // 4 KB
    __shared__ __align__(16) float s_emb[KN][DD];            // 5 KB
    __shared__ __align__(16) float s_st[TT];                 // 0.5 KB
    __shared__ float s_part[4][RMAX][KN];                    // 0.64 KB
    __shared__ unsigned s_maskA[RMAX];
    __shared__ int s_invA[RMAX];

    const int b = blockIdx.x, tid = threadIdx.x;
    const float t_src = timestamps[b];

    if (tid < TT) s_st[tid] = __cosf(tb[tid]);
    __syncthreads();

    // ===== hop-2 rows (layer 0): 3 weight passes of 4/4/2 rows =====
    stage_hop2(tid, b, 0, 4, t_src, nbr2, nbr1, eid1, et1, nf, mem, ef, tw, tb,
               s_st, s_qin, s_pool, s_maskA, s_invA);
    __syncthreads();
    attn_rows<4>(tid, s_qin, s_pool, s_maskA, s_invA, s_part,
                 Wq, bq, Wk, bk, Wv, bv, Wo, bo, f1w, f1b, f2w, f2b,
                 &s_emb[0][0]);

    stage_hop2(tid, b, 4, 4, t_src, nbr2, nbr1, eid1, et1, nf, mem, ef, tw, tb,
               s_st, s_qin, s_pool, s_maskA, s_invA);
    __syncthreads();
    attn_rows<4>(tid, s_qin, s_pool, s_maskA, s_invA, s_part,
                 Wq, bq, Wk, bk, Wv, bv, Wo, bo, f1w, f1b, f2w, f2b,
                 &s_emb[4][0]);

    stage_hop2(tid, b, 8, 2, t_src, nbr2, nbr1, eid1, et1, nf, mem, ef, tw, tb,
               s_st, s_qin, s_pool, s_maskA, s_invA);
    __syncthreads();
    attn_rows<2>(tid, s_qin, s_pool, s_maskA, s_invA, s_part,
                 Wq, bq, Wk, bk, Wv, bv, Wo, bo, f1w, f1b, f2w, f2b,
                 &s_emb[8][0]);

    // ===== top row (layer 1) =====
    {
        const int src = source_nodes[b];
        for (int idx = tid; idx < QDIM / 4; idx += BLK) {
            const int e = idx * 4;
            float4 v;
            if (e < DD) {
                const float4 A = *(const float4*)&nf[(long)src * DD + e];
                const float4 C = *(const float4*)&mem[(long)src * DD + e];
                v = make_float4(A.x + C.x, A.y + C.y, A.z + C.z, A.w + C.w);
            } else {
                v = *(const float4*)&s_st[e - DD];
            }
            *(float4*)&s_qin[e] = v;
        }
        if (tid == 0) {
            unsigned m = 0;
            for (int kk = 0; kk < KN; ++kk)
                if (nbr2[b * KN + kk] == 0) m |= (1u << kk);
            int inv = (m == ((1u << KN) - 1));
            if (inv) m &= ~(1u << (KN - 1));
            s_maskA[0] = m; s_invA[0] = inv;
        }
        for (int widx = tid; widx < KN * (KDIM / 4); widx += BLK) {
            const int kk = widx / (KDIM / 4);
            const int g  = widx - kk * (KDIM / 4);
            const int e  = g * 4;
            float4 val;
            if (e < DD) {
                val = *(const float4*)&s_emb[kk][e];
            } else if (e < 2 * DD) {
                const long eid = eid2[b * KN + kk];
                val = *(const float4*)&ef[eid * DD + (e - DD)];
            } else {
                const int t = e - 2 * DD;
                const float dt = t_src - et2[b * KN + kk];
                val = make_float4(__cosf(dt * tw[t]     + tb[t]),
                                  __cosf(dt * tw[t + 1] + tb[t + 1]),
                                  __cosf(dt * tw[t + 2] + tb[t + 2]),
                                  __cosf(dt * tw[t + 3] + tb[t + 3]));
            }
            *(float4*)&s_pool[kk * KDIM + e] = val;
        }
        __syncthreads();
        attn_rows<1>(tid, s_qin, s_pool, s_maskA, s_invA, s_part,
                     Wq + QDIM * QDIM, bq + QDIM,
                     Wk + QDIM * KDIM, bk + QDIM,
                     Wv + QDIM * KDIM, bv + QDIM,
                     Wo + QDIM * QDIM, bo + QDIM,
                     f1w + DD * (QDIM + DD), f1b + DD,
                     f2w + DD * DD, f2b + DD,
                     out + (long)b * DD);
    }
}

extern "C" void kernel_launch(void* const* d_in, const int* in_sizes, int n_in,
                              void* d_out, int out_size, void* d_ws, size_t ws_size,
                              hipStream_t stream) {
    const float* nf  = (const float*)d_in[0];
    const float* mem = (const float*)d_in[1];
    const float* ef  = (const float*)d_in[2];
    const float* tw  = (const float*)d_in[3];
    const float* tb  = (const float*)d_in[4];
    const float* Wq  = (const float*)d_in[5];
    const float* bq  = (const float*)d_in[6];
    const float* Wk  = (const float*)d_in[7];
    const float* bk  = (const float*)d_in[8];
    const float* Wv  = (const float*)d_in[9];
    const float* bv  = (const float*)d_in[10];
    const float* Wo  = (const float*)d_in[11];
    const float* bo  = (const float*)d_in[12];
    const float* f1w = (const float*)d_in[13];
    const float* f1b = (const float*)d_in[14];
    const float* f2w = (const float*)d_in[15];
    const float* f2b = (const float*)d_in[16];
    const int* src_nodes = (const int*)d_in[17];
    const float* ts  = (const float*)d_in[18];
    const int* nbr2  = (const int*)d_in[19];
    const int* eid2  = (const int*)d_in[20];
    const float* et2 = (const float*)d_in[21];
    const int* nbr1  = (const int*)d_in[22];
    const int* eid1  = (const int*)d_in[23];
    const float* et1 = (const float*)d_in[24];

    const int B = in_sizes[17];   // 2048

    tgn_fused<<<B, BLK, 0, stream>>>(
        src_nodes, ts, nbr2, eid2, et2, nbr1, eid1, et1,
        nf, mem, ef, tw, tb,
        Wq, bq, Wk, bk, Wv, bv, Wo, bo,
        f1w, f1b, f2w, f2b,
        (float*)d_out);
}